// Round 6
// baseline (395.540 us; speedup 1.0000x reference)
//
#include <hip/hip_runtime.h>
#include <math.h>

// STC loss forward on MI355X — Round 18: single kernel, producer-consumer
// waves per block. No cooperative launch (R17 killed the container — coop
// launch + graph capture is the suspect; never again). No tabA/tabB: the
// 84MB emission round-trip is gone.
//
// Structure: 32 blocks (one per batch) x 4 waves:
//   wave0: forward scan consumer  (chunks 0..62, rows 0..1007)
//   wave1: backward scan consumer (chunks 0..61, rows 1008..1999)
//   wave2: forward emission producer -> LDS double buffer
//   wave3: backward emission producer -> LDS double buffer
// Per iteration k: consumers eat chunk k from LDS buf[k&1] while producers
// build chunk k+1 into buf[(k+1)&1]; one __syncthreads per iteration.
// Barrier count uniform across waves: 1 (zero-init) + 1 (prologue) + 63
// (loop) + 1 (epilogue) — producers/consumers idle-but-barrier on tail iters.
//
// Consumers stage each chunk via pinned inline-asm ds_read_b128 + counted
// lgkmcnt(0) + sched_barrier (rule #18), then run 16 pure-VALU steps
// (math identical to R16, which passed with absmax 0).
// Producers pipeline 16 global_load_dwordx2 per chunk (X/Y parity,
// vmcnt(16)) — R15/R16's proven load-pipeline pattern — then compute the
// emission row math (bit-identical to the old emit kernel) into LDS.
//
// Per column (lane j owns cols 2j,2j+1), log2 domain:
//   fwd: m=max(A,P); lz=log2(1+2^-|A-P|); A'=(m+lq)+lz; O'=(sk?(m+tok)+lz:A+tok)
//   bwd: x=lq+bA; y=tok+bO; L=LSE2(x,y); bA'=L (x at col100); bO'_{j-1}=sk?L:x
// combine at t*=1007/1008 boundary: LSE_s(alpha[s]+beta[s]) * ln2.

#define T_LEN   2000
#define BATCH   32
#define NCLS    128
#define LTGT    100
#define NEG_INF_F (-1e30f)

typedef float f32x4 __attribute__((ext_vector_type(4)));
typedef float f32x2 __attribute__((ext_vector_type(2)));

#if __has_builtin(__builtin_amdgcn_exp2f)
#define EXP2(x) __builtin_amdgcn_exp2f(x)
#else
#define EXP2(x) exp2f(x)
#endif
#if __has_builtin(__builtin_amdgcn_logf)
#define LOG2(x) __builtin_amdgcn_logf(x)
#else
#define LOG2(x) __log2f(x)
#endif

// DPP wave shifts, lane-boundary value = NEG_INF via old + bound_ctrl=false.
__device__ __forceinline__ float shift_up1_ninf(float x)  // lane i <- i-1
{
    return __int_as_float(
        __builtin_amdgcn_update_dpp(__float_as_int(NEG_INF_F),
                                    __float_as_int(x), 0x138, 0xf, 0xf, false));
}
__device__ __forceinline__ float shift_dn1_ninf(float x)  // lane i <- i+1
{
    return __int_as_float(
        __builtin_amdgcn_update_dpp(__float_as_int(NEG_INF_F),
                                    __float_as_int(x), 0x130, 0xf, 0xf, false));
}

// LDS byte-offset of a __shared__ address (generic -> AS3 -> 32-bit).
__device__ __forceinline__ unsigned ldsa(const void* p)
{
    return (unsigned)(unsigned long long)
        (const __attribute__((address_space(3))) char*)p;
}

// pinned-issue loads + counted manual waits (proven R15/R16 pattern)
#define GL2(dst, base)                                                  \
    asm volatile("global_load_dwordx2 %0, %1, off"                      \
                 : "=&v"(dst) : "v"(base))
#define DSR4(dst, addr, imm)                                            \
    asm volatile("ds_read_b128 %0, %1 offset:" #imm                     \
                 : "=&v"(dst) : "v"(addr))
#define VMWAIT(n) do {                                                  \
        asm volatile("s_waitcnt vmcnt(" #n ")" ::: "memory");           \
        __builtin_amdgcn_sched_barrier(0);                              \
    } while (0)
#define LGKMWAIT() do {                                                 \
        asm volatile("s_waitcnt lgkmcnt(0)" ::: "memory");              \
        __builtin_amdgcn_sched_barrier(0);                              \
    } while (0)

__global__ void __launch_bounds__(256, 1)
stc_fused(const float* __restrict__ inputs,   // (T,B,C) log-softmax (natural)
          const int*   __restrict__ targets,  // (B,L)
          float*       __restrict__ out,
          const float wt)
{
    const int b    = blockIdx.x;
    const int lane = threadIdx.x & 63;
    const int wave = threadIdx.x >> 6;
    const bool l50 = (lane == 50);

    // [dir][buf][row][slot] — rows padded to 64 float4 so lanes 50..63 read
    // in-bounds (values unused / contained; zero-initialized below).
    __shared__ float4 emisA[2][2][16][64];              // 64 KiB
    __shared__ __align__(16) float emisQ[2][2][16];     // 256 B
    __shared__ float lps[2][16][NCLS];                  // 16 KiB
    __shared__ float sb[4][64];

    // per-lane constants (all waves compute; producers use tg, consumers skb)
    const int tb0 = b * LTGT;
    const int c0 = 2 * lane, c1 = 2 * lane + 1;
    bool skb0 = false, skb1 = false;
    if (c0 >= 1 && c0 <= 99)
        skb0 = (targets[tb0 + c0] != targets[tb0 + c0 - 1]);
    if (c1 <= 99)
        skb1 = (targets[tb0 + c1] != targets[tb0 + c1 - 1]);
    int tg0 = 0, tg1 = 0;
    if (lane < 50) {
        tg0 = targets[tb0 + c0];
        tg1 = targets[tb0 + c1];
    }

    const float L2E = 1.4426950408889634f;
    const float wtp = wt * (1.0f + 1e-7f);
    const char* inSrc = (const char*)inputs + (size_t)b * 512
                      + (size_t)lane * 8;

    // zero-init emission buffers (NaN insurance for pad slots)
    {
        const float4 z4 = make_float4(0.f, 0.f, 0.f, 0.f);
        float4* ea = (float4*)emisA;
        for (int i = threadIdx.x; i < 2 * 2 * 16 * 64; i += 256) ea[i] = z4;
        float* eq = (float*)emisQ;
        if (threadIdx.x < 64) eq[threadIdx.x] = 0.f;
    }

    // ---------------- producer machinery ----------------
    // chunk c (dir 0/fwd): rows 16c..16c+15 ; (dir 1/bwd): 1984-16c .. +15
#define PTROW(dir, c) ((dir) ? (1984 - 16 * (c)) : (16 * (c)))
#define LOADP(S, trow) do {                                             \
        const char* p_ = inSrc + (size_t)(trow) * 16384;                \
        GL2(S##0,  p_);            GL2(S##1,  p_ + 16384);              \
        GL2(S##2,  p_ + 32768);    GL2(S##3,  p_ + 49152);              \
        GL2(S##4,  p_ + 65536);    GL2(S##5,  p_ + 81920);              \
        GL2(S##6,  p_ + 98304);    GL2(S##7,  p_ + 114688);             \
        GL2(S##8,  p_ + 131072);   GL2(S##9,  p_ + 147456);             \
        GL2(S##10, p_ + 163840);   GL2(S##11, p_ + 180224);             \
        GL2(S##12, p_ + 196608);   GL2(S##13, p_ + 212992);             \
        GL2(S##14, p_ + 229376);   GL2(S##15, p_ + 245760);             \
    } while (0)

    // one emission row: math bit-identical to the old emit kernel
#define PROW(i, X, dir, bi) do {                                        \
        *(float2*)&lps[dir][i][2 * lane] = make_float2(X[0], X[1]);     \
        const float ex_ = __expf(X[0]);                                 \
        float ps_ = (lane == 0) ? __expf(X[1]) : ex_ + __expf(X[1]);    \
        ps_ += __shfl_xor(ps_, 32, 64);                                 \
        ps_ += __shfl_xor(ps_, 16, 64);                                 \
        ps_ += __shfl_xor(ps_, 8, 64);                                  \
        ps_ += __shfl_xor(ps_, 4, 64);                                  \
        ps_ += __shfl_xor(ps_, 2, 64);                                  \
        ps_ += __shfl_xor(ps_, 1, 64);                                  \
        const float pb_ = __shfl(ex_, 0, 64);                           \
        if (lane < 50) {                                                \
            const float lt0_ = lps[dir][i][tg0];                        \
            const float lt1_ = lps[dir][i][tg1];                        \
            const float aa_  = fmaf(wtp, ps_, pb_);                     \
            const float q0_  = fmaf(-wt, __expf(lt0_), aa_);            \
            const float q1_  = fmaf(-wt, __expf(lt1_), aa_);            \
            emisA[dir][bi][i][lane] =                                   \
                make_float4(L2E * lt0_, L2E * lt1_, LOG2(q0_), LOG2(q1_)); \
        } else if (lane == 50) {                                        \
            emisQ[dir][bi][i] = LOG2(fmaf(wt, ps_, pb_));               \
        }                                                               \
    } while (0)

#define PROWS(S, dir, bi) do {                                          \
        PROW(0,  S##0,  dir, bi); PROW(1,  S##1,  dir, bi);             \
        PROW(2,  S##2,  dir, bi); PROW(3,  S##3,  dir, bi);             \
        PROW(4,  S##4,  dir, bi); PROW(5,  S##5,  dir, bi);             \
        PROW(6,  S##6,  dir, bi); PROW(7,  S##7,  dir, bi);             \
        PROW(8,  S##8,  dir, bi); PROW(9,  S##9,  dir, bi);             \
        PROW(10, S##10, dir, bi); PROW(11, S##11, dir, bi);             \
        PROW(12, S##12, dir, bi); PROW(13, S##13, dir, bi);             \
        PROW(14, S##14, dir, bi); PROW(15, S##15, dir, bi);             \
    } while (0)

    // producer register sets (chunk parity: even chunks in eA, odd in eB)
    f32x2 eA0, eA1, eA2, eA3, eA4, eA5, eA6, eA7,
          eA8, eA9, eA10, eA11, eA12, eA13, eA14, eA15;
    f32x2 eB0, eB1, eB2, eB3, eB4, eB5, eB6, eB7,
          eB8, eB9, eB10, eB11, eB12, eB13, eB14, eB15;

    const int pdir  = wave - 2;              // valid when wave>=2
    const int plast = (wave == 3) ? 61 : 62; // last chunk index per dir

    if (wave >= 2) {                         // issue chunk 0+1 loads early
        LOADP(eA, PTROW(pdir, 0));
        LOADP(eB, PTROW(pdir, 1));
    }

    __syncthreads();                         // zero-init complete

    if (wave >= 2) {                         // produce chunk 0 into buf 0
        VMWAIT(16);                          // eA (chunk0) done, eB in flight
        PROWS(eA, pdir, 0);
    }

    __syncthreads();                         // buf0 ready

    // ---------------- consumer state ----------------
    float A0 = (lane == 0) ? 0.0f : NEG_INF_F;
    float O0 = NEG_INF_F, A1 = NEG_INF_F, O1 = NEG_INF_F;
    float p0 = NEG_INF_F;
    float bA0 = l50 ? 0.0f : NEG_INF_F;              // bA[100] = 0
    float bA1 = NEG_INF_F;
    float bO0 = NEG_INF_F;
    float bO1 = (lane == 49) ? 0.0f : NEG_INF_F;     // bO[99] = 0

    // staged chunk registers (shared names across consumer waves)
    f32x4 Xv0, Xv1, Xv2, Xv3, Xv4, Xv5, Xv6, Xv7,
          Xv8, Xv9, Xv10, Xv11, Xv12, Xv13, Xv14, Xv15, Xq0, Xq1, Xq2, Xq3;

#define STAGEC(dir, bi) do {                                            \
        const unsigned a_ = ldsa(&emisA[dir][bi][0][lane]);             \
        DSR4(Xv0,  a_, 0);     DSR4(Xv1,  a_, 1024);                    \
        DSR4(Xv2,  a_, 2048);  DSR4(Xv3,  a_, 3072);                    \
        DSR4(Xv4,  a_, 4096);  DSR4(Xv5,  a_, 5120);                    \
        DSR4(Xv6,  a_, 6144);  DSR4(Xv7,  a_, 7168);                    \
        DSR4(Xv8,  a_, 8192);  DSR4(Xv9,  a_, 9216);                    \
        DSR4(Xv10, a_, 10240); DSR4(Xv11, a_, 11264);                   \
        DSR4(Xv12, a_, 12288); DSR4(Xv13, a_, 13312);                   \
        DSR4(Xv14, a_, 14336); DSR4(Xv15, a_, 15360);                   \
        const unsigned q_ = ldsa(&emisQ[dir][bi][0]);                   \
        DSR4(Xq0, q_, 0);  DSR4(Xq1, q_, 16);                           \
        DSR4(Xq2, q_, 32); DSR4(Xq3, q_, 48);                           \
        LGKMWAIT();                                                     \
    } while (0)

#define FSTEP(vx, vy, vz, vw, qk) do {                                 \
        const float m1  = fmaxf(A1, O0);                               \
        const float lz1 = LOG2(1.0f + EXP2(-fabsf(A1 - O0)));          \
        const float O1n = skb1 ? (m1 + (vy)) + lz1 : A1 + (vy);        \
        const float psh = shift_up1_ninf(O1n);                         \
        A1 = (m1 + (vw)) + lz1;                                        \
        O1 = O1n;                                                      \
        const float m0  = fmaxf(A0, p0);                               \
        const float lz0 = LOG2(1.0f + EXP2(-fabsf(A0 - p0)));          \
        const float lq0 = l50 ? (qk) : (vz);                           \
        O0 = skb0 ? (m0 + (vx)) + lz0 : A0 + (vx);                     \
        A0 = (m0 + lq0) + lz0;                                         \
        p0 = psh;                                                      \
    } while (0)
#define RUNF() do {                                                        \
        FSTEP(Xv0[0],  Xv0[1],  Xv0[2],  Xv0[3],  Xq0[0]);                 \
        FSTEP(Xv1[0],  Xv1[1],  Xv1[2],  Xv1[3],  Xq0[1]);                 \
        FSTEP(Xv2[0],  Xv2[1],  Xv2[2],  Xv2[3],  Xq0[2]);                 \
        FSTEP(Xv3[0],  Xv3[1],  Xv3[2],  Xv3[3],  Xq0[3]);                 \
        FSTEP(Xv4[0],  Xv4[1],  Xv4[2],  Xv4[3],  Xq1[0]);                 \
        FSTEP(Xv5[0],  Xv5[1],  Xv5[2],  Xv5[3],  Xq1[1]);                 \
        FSTEP(Xv6[0],  Xv6[1],  Xv6[2],  Xv6[3],  Xq1[2]);                 \
        FSTEP(Xv7[0],  Xv7[1],  Xv7[2],  Xv7[3],  Xq1[3]);                 \
        FSTEP(Xv8[0],  Xv8[1],  Xv8[2],  Xv8[3],  Xq2[0]);                 \
        FSTEP(Xv9[0],  Xv9[1],  Xv9[2],  Xv9[3],  Xq2[1]);                 \
        FSTEP(Xv10[0], Xv10[1], Xv10[2], Xv10[3], Xq2[2]);                 \
        FSTEP(Xv11[0], Xv11[1], Xv11[2], Xv11[3], Xq2[3]);                 \
        FSTEP(Xv12[0], Xv12[1], Xv12[2], Xv12[3], Xq3[0]);                 \
        FSTEP(Xv13[0], Xv13[1], Xv13[2], Xv13[3], Xq3[1]);                 \
        FSTEP(Xv14[0], Xv14[1], Xv14[2], Xv14[3], Xq3[2]);                 \
        FSTEP(Xv15[0], Xv15[1], Xv15[2], Xv15[3], Xq3[3]);                 \
    } while (0)

#define BSTEP(vx, vy, vz, vw, qk) do {                                 \
        const float x1  = bA1 + (vw);                                  \
        const float y1  = bO1 + (vy);                                  \
        const float m1  = fmaxf(x1, y1);                               \
        const float lz1 = LOG2(1.0f + EXP2(-fabsf(x1 - y1)));          \
        const float L1  = m1 + lz1;                                    \
        const float lq0 = l50 ? (qk) : (vz);                           \
        const float x0  = bA0 + lq0;                                   \
        const float y0  = bO0 + (vx);                                  \
        const float m0  = fmaxf(x0, y0);                               \
        const float lz0 = LOG2(1.0f + EXP2(-fabsf(x0 - y0)));          \
        const float L0  = m0 + lz0;                                    \
        const float t0  = skb0 ? L0 : x0;                              \
        const float psh = shift_dn1_ninf(t0);  /* lane i <- i+1 */     \
        bO0 = skb1 ? L1 : x1;                                          \
        bA0 = l50 ? x0 : L0;                                           \
        bA1 = L1;                                                      \
        bO1 = psh;                                                     \
    } while (0)
#define RUNBK() do {                                                       \
        BSTEP(Xv15[0], Xv15[1], Xv15[2], Xv15[3], Xq3[3]);                 \
        BSTEP(Xv14[0], Xv14[1], Xv14[2], Xv14[3], Xq3[2]);                 \
        BSTEP(Xv13[0], Xv13[1], Xv13[2], Xv13[3], Xq3[1]);                 \
        BSTEP(Xv12[0], Xv12[1], Xv12[2], Xv12[3], Xq3[0]);                 \
        BSTEP(Xv11[0], Xv11[1], Xv11[2], Xv11[3], Xq2[3]);                 \
        BSTEP(Xv10[0], Xv10[1], Xv10[2], Xv10[3], Xq2[2]);                 \
        BSTEP(Xv9[0],  Xv9[1],  Xv9[2],  Xv9[3],  Xq2[1]);                 \
        BSTEP(Xv8[0],  Xv8[1],  Xv8[2],  Xv8[3],  Xq2[0]);                 \
        BSTEP(Xv7[0],  Xv7[1],  Xv7[2],  Xv7[3],  Xq1[3]);                 \
        BSTEP(Xv6[0],  Xv6[1],  Xv6[2],  Xv6[3],  Xq1[2]);                 \
        BSTEP(Xv5[0],  Xv5[1],  Xv5[2],  Xv5[3],  Xq1[1]);                 \
        BSTEP(Xv4[0],  Xv4[1],  Xv4[2],  Xv4[3],  Xq1[0]);                 \
        BSTEP(Xv3[0],  Xv3[1],  Xv3[2],  Xv3[3],  Xq0[3]);                 \
        BSTEP(Xv2[0],  Xv2[1],  Xv2[2],  Xv2[3],  Xq0[2]);                 \
        BSTEP(Xv1[0],  Xv1[1],  Xv1[2],  Xv1[3],  Xq0[1]);                 \
        BSTEP(Xv0[0],  Xv0[1],  Xv0[2],  Xv0[3],  Xq0[0]);                 \
    } while (0)

    // ---------------- main pipeline: 63 iterations ----------------
    for (int k = 0; k < 63; ++k) {
        if (wave == 0) {                         // fwd consume chunk k
            STAGEC(0, (k & 1));
            RUNF();
        } else if (wave == 1) {                  // bwd consume chunk k
            if (k < 62) {
                STAGEC(1, (k & 1));
                RUNBK();
            }
        } else {                                 // produce chunk c = k+1
            const int c = k + 1;
            if (c <= plast) {
                const int cn = c + 1;
                if (cn <= plast) {
                    if (cn & 1) { LOADP(eB, PTROW(pdir, cn)); }
                    else        { LOADP(eA, PTROW(pdir, cn)); }
                    VMWAIT(16);                  // set-c done, set-cn flying
                } else {
                    VMWAIT(0);                   // tail: drain set-c
                }
                if (c & 1) PROWS(eB, pdir, (c & 1));
                else       PROWS(eA, pdir, (c & 1));
            }
        }
        __syncthreads();
    }

    // ---------------- combine ----------------
    if (wave == 1) {
        sb[0][lane] = bA0; sb[1][lane] = bA1;
        sb[2][lane] = bO0; sb[3][lane] = bO1;
    }
    __syncthreads();

    if (wave == 0) {
        const float bA0g = sb[0][lane], bA1g = sb[1][lane];
        const float bO0g = sb[2][lane], bO1g = sb[3][lane];
        const float T0 = (lane <= 50) ? A0 + bA0g : NEG_INF_F;
        const float T1 = (lane < 50)  ? A1 + bA1g : NEG_INF_F;
        const float T2 = (lane < 50)  ? O0 + bO0g : NEG_INF_F;
        const float T3 = (lane < 50)  ? O1 + bO1g : NEG_INF_F;
        float M = fmaxf(fmaxf(T0, T1), fmaxf(T2, T3));
        float S = EXP2(T0 - M) + EXP2(T1 - M) + EXP2(T2 - M) + EXP2(T3 - M);
        #pragma unroll
        for (int off = 32; off >= 1; off >>= 1) {
            const float Mo = __shfl_xor(M, off, 64);
            const float So = __shfl_xor(S, off, 64);
            const float Mn = fmaxf(M, Mo);
            S = S * EXP2(M - Mn) + So * EXP2(Mo - Mn);
            M = Mn;
        }
        if (lane == 0) {
            const float LN2 = 0.6931471805599453f;
            atomicAdd(out, -(M + LOG2(S)) * LN2
                               / ((float)T_LEN * (float)BATCH));
        }
    }
}

// ---------------------------------------------------------------- launch
extern "C" void kernel_launch(void* const* d_in, const int* in_sizes, int n_in,
                              void* d_out, int out_size, void* d_ws, size_t ws_size,
                              hipStream_t stream)
{
    const float* inputs  = (const float*)d_in[0];   // (2000,32,128) f32
    const int*   targets = (const int*)d_in[1];     // (32,100) i32
    float*       out     = (float*)d_out;           // scalar f32
    (void)d_ws; (void)ws_size;

    // wt = WLAST + (W0-WLAST)*exp(-NSTEP*ln2/THALF)
    const float wt = (float)(0.1 + 0.9 * exp(-log(2.0) / 10000.0));

    (void)hipMemsetAsync(out, 0, sizeof(float), stream);
    stc_fused<<<dim3(BATCH), dim3(256), 0, stream>>>(inputs, targets, out, wt);
}

// Round 9
// 132.077 us; speedup vs baseline: 2.9948x; 2.9948x over previous
//
#include <hip/hip_runtime.h>
#include <math.h>

// STC loss forward on MI355X — Round 21: revert to the PROVEN R16 log-domain
// bidirectional scan; polish only.
//
// R19/R20 post-mortem: exp-domain (linear) scan failed accuracy twice
// (2.7e-3, then 0.205 with per-lane scales) — closed permanently.
//
// R16 accounting: 138.5us = 64.7 harness (measured via R18's single fused
// dispatch) + 60.7 scan + ~13 emit/memset. Scan is ISSUE-bound:
// ~25 VALU x 2cy + 4 trans x 8cy (quarter-rate) ~ 72 cy/step.
// Polish: (1) shared ml=m+lz in FSTEP (R13's exact proven ordering):
// O'=(sk?ml:A)+tok, A'=ml+lq — saves 4 VALU adds/step (~8 cy);
// (2) emit's idle lane 51 (block 0,0) zeroes *out — drops the memset
// dispatch from the graph.
//
// Everything else is R16 verbatim (passed, absmax 0):
//   fwd : m=max(A,P); lz=log2(1+2^-|A-P|); ml=m+lz; A'=ml+lq;
//         O'=(sk?ml:A)+tok ; O1->p0 via DPP wave_shr:1, old=-inf
//   bwd : x=lq+bA; y=tok+bO; L=LSE2(x,y); bA'=L (x at col100);
//         bO'_{j-1}=sk?L:x  via DPP wave_shl:1, old=-inf
//   combine at t*=1007/1008: LSE_s(alpha[s]+beta[s]) * ln2.

#define T_LEN   2000
#define BATCH   32
#define NCLS    128
#define LTGT    100
#define CHUNK   16
#define EROWS   8
#define NEG_INF_F (-1e30f)

typedef float f32x4 __attribute__((ext_vector_type(4)));

#if __has_builtin(__builtin_amdgcn_exp2f)
#define EXP2(x) __builtin_amdgcn_exp2f(x)
#else
#define EXP2(x) exp2f(x)
#endif
#if __has_builtin(__builtin_amdgcn_logf)
#define LOG2(x) __builtin_amdgcn_logf(x)
#else
#define LOG2(x) __log2f(x)
#endif

// ---------------------------------------------------------------- K1: emissions
// tabA[(b*T+t)*50 + j] = (L2E*tok_2j, L2E*tok_2j+1, log2 q_2j, log2 q_2j+1)
// tabB[b*T+t] = log2(p_blank + wt*s)
__global__ void __launch_bounds__(64)
stc_emit(const float* __restrict__ inputs,   // (T,B,C) log-softmax (natural)
         const int*   __restrict__ targets,  // (B,L)
         float4*      __restrict__ tabA,
         float*       __restrict__ tabB,
         float*       __restrict__ out,
         const float wt)
{
    const int tbase = blockIdx.x * EROWS;
    const int b     = blockIdx.y;
    const int lane  = threadIdx.x;       // 1 wave per block, 8 rows per wave

    __shared__ float lps[EROWS][NCLS];

    // fold the output zeroing into this kernel (idle lane): one fewer
    // dispatch in the graph. emit completes before scan starts (stream order).
    if (blockIdx.x == 0 && blockIdx.y == 0 && lane == 51) *out = 0.0f;

    int tg0 = 0, tg1 = 0;
    if (lane < 50) {                     // same gather indices for all rows
        tg0 = targets[b * LTGT + 2 * lane];
        tg1 = targets[b * LTGT + 2 * lane + 1];
    }
    const float L2E = 1.4426950408889634f;

    // phase A: 8 independent global loads (one HBM latency for all)
#define ELD(i) const float2 x##i = *(const float2*)(inputs +                 \
                   ((size_t)(tbase + (i)) * BATCH + b) * NCLS + 2 * lane);
    ELD(0) ELD(1) ELD(2) ELD(3) ELD(4) ELD(5) ELD(6) ELD(7)
#undef ELD
    // phase A2: LDS writes (same-wave DS: in-order)
#define EST(i) *(float2*)&lps[i][2 * lane] = x##i;
    EST(0) EST(1) EST(2) EST(3) EST(4) EST(5) EST(6) EST(7)
#undef EST
    // phase B: per-lane partials (bit-identical to R16 per-row math)
#define EPART(i) const float ex##i = __expf(x##i.x);                          \
                 float p##i = (lane == 0) ? __expf(x##i.y)                    \
                                          : ex##i + __expf(x##i.y);
    EPART(0) EPART(1) EPART(2) EPART(3) EPART(4) EPART(5) EPART(6) EPART(7)
#undef EPART
    // phase C: butterflies, LEVEL-major (8 independent shfls per level)
#define ERED(off) p0 += __shfl_xor(p0, off, 64); p1 += __shfl_xor(p1, off, 64);\
                  p2 += __shfl_xor(p2, off, 64); p3 += __shfl_xor(p3, off, 64);\
                  p4 += __shfl_xor(p4, off, 64); p5 += __shfl_xor(p5, off, 64);\
                  p6 += __shfl_xor(p6, off, 64); p7 += __shfl_xor(p7, off, 64);
    ERED(32) ERED(16) ERED(8) ERED(4) ERED(2) ERED(1)
#undef ERED
#define EPB(i) const float pb##i = __shfl(ex##i, 0, 64);
    EPB(0) EPB(1) EPB(2) EPB(3) EPB(4) EPB(5) EPB(6) EPB(7)
#undef EPB

    if (lane < 50) {
#define EOUT(i) do {                                                          \
        const float lt0 = lps[i][tg0], lt1 = lps[i][tg1];                     \
        const float aa  = fmaf(wt * (1.0f + 1e-7f), p##i, pb##i);             \
        const float q0  = fmaf(-wt, __expf(lt0), aa);                         \
        const float q1  = fmaf(-wt, __expf(lt1), aa);                         \
        tabA[((size_t)b * T_LEN + tbase + (i)) * 50 + lane] =                 \
            make_float4(L2E * lt0, L2E * lt1, LOG2(q0), LOG2(q1));            \
    } while (0);
        EOUT(0) EOUT(1) EOUT(2) EOUT(3) EOUT(4) EOUT(5) EOUT(6) EOUT(7)
#undef EOUT
    } else if (lane == 50) {
#define EOB(i) tabB[(size_t)b * T_LEN + tbase + (i)] =                        \
                   LOG2(fmaf(wt, p##i, pb##i));
        EOB(0) EOB(1) EOB(2) EOB(3) EOB(4) EOB(5) EOB(6) EOB(7)
#undef EOB
    }
}

// DPP wave shifts, lane-boundary value = NEG_INF via old + bound_ctrl=false.
__device__ __forceinline__ float shift_up1_ninf(float x)  // lane i <- i-1
{
    return __int_as_float(
        __builtin_amdgcn_update_dpp(__float_as_int(NEG_INF_F),
                                    __float_as_int(x), 0x138, 0xf, 0xf, false));
}
__device__ __forceinline__ float shift_dn1_ninf(float x)  // lane i <- i+1
{
    return __int_as_float(
        __builtin_amdgcn_update_dpp(__float_as_int(NEG_INF_F),
                                    __float_as_int(x), 0x130, 0xf, 0xf, false));
}

// pinned-issue async load (bare ext_vector output) + counted manual waits
#define GL4(dst, base, imm)                                             \
    asm volatile("global_load_dwordx4 %0, %1, off offset:" #imm         \
                 : "=&v"(dst) : "v"(base))
#define VMWAIT(n) do {                                                  \
        asm volatile("s_waitcnt vmcnt(" #n ")" ::: "memory");           \
        __builtin_amdgcn_sched_barrier(0);                              \
    } while (0)

// ---------------------------------------------------------------- K2: scan
__global__ void __launch_bounds__(128, 1)
stc_scan(const float4* __restrict__ tabA,
         const float*  __restrict__ tabB,
         const int*    __restrict__ targets,
         float*        __restrict__ out)
{
    const int b    = blockIdx.x;
    const int lane = threadIdx.x & 63;       // lane j owns cols 2j, 2j+1
    const int wave = threadIdx.x >> 6;       // 0 = forward, 1 = backward
    const bool l50 = (lane == 50);

    __shared__ float sb[4][64];              // beta handoff

    // skip gates (same masks serve fwd O'-gate and bwd t-gate)
    const int tb0 = b * LTGT;
    const int c0 = 2 * lane, c1 = 2 * lane + 1;
    bool skb0 = false, skb1 = false;
    if (c0 >= 1 && c0 <= 99)
        skb0 = (targets[tb0 + c0] != targets[tb0 + c0 - 1]);
    if (c1 <= 99)
        skb1 = (targets[tb0 + c1] != targets[tb0 + c1 - 1]);

    const char* gAc = (const char*)tabA + (size_t)b * T_LEN * 800
                    + (size_t)lane * 16;
    const char* gQc = (const char*)(tabB + (size_t)b * T_LEN);

    // drain compiler-issued loads so manual vmcnt counts are exact
    asm volatile("s_waitcnt vmcnt(0) lgkmcnt(0)" ::: "memory");
    __builtin_amdgcn_sched_barrier(0);

    f32x4 Xv0, Xv1, Xv2, Xv3, Xv4, Xv5, Xv6, Xv7,
          Xv8, Xv9, Xv10, Xv11, Xv12, Xv13, Xv14, Xv15, Xq0, Xq1, Xq2, Xq3;
    f32x4 Yv0, Yv1, Yv2, Yv3, Yv4, Yv5, Yv6, Yv7,
          Yv8, Yv9, Yv10, Yv11, Yv12, Yv13, Yv14, Yv15, Yq0, Yq1, Yq2, Yq3;

    // 20 loads per chunk; trow = starting time-row of the chunk
#define LOADB(P, trow) do {                                             \
        const char* a0_ = gAc + (size_t)(trow) * 800;                   \
        const char* a1_ = a0_ + 4000;                                   \
        const char* a2_ = a0_ + 8000;                                   \
        GL4(P##v0,  a0_, 0);    GL4(P##v1,  a0_, 800);                  \
        GL4(P##v2,  a0_, 1600); GL4(P##v3,  a0_, 2400);                 \
        GL4(P##v4,  a0_, 3200);                                         \
        GL4(P##v5,  a1_, 0);    GL4(P##v6,  a1_, 800);                  \
        GL4(P##v7,  a1_, 1600); GL4(P##v8,  a1_, 2400);                 \
        GL4(P##v9,  a1_, 3200);                                         \
        GL4(P##v10, a2_, 0);    GL4(P##v11, a2_, 800);                  \
        GL4(P##v12, a2_, 1600); GL4(P##v13, a2_, 2400);                 \
        GL4(P##v14, a2_, 3200); GL4(P##v15, a2_, 4000);                 \
        const char* q_ = gQc + (size_t)(trow) * 4;                      \
        GL4(P##q0, q_, 0);  GL4(P##q1, q_, 16);                         \
        GL4(P##q2, q_, 32); GL4(P##q3, q_, 48);                         \
    } while (0)

    // forward alpha state (wave0) — declared here so combine can read them
    float A0 = (lane == 0) ? 0.0f : NEG_INF_F;
    float O0 = NEG_INF_F, A1 = NEG_INF_F, O1 = NEG_INF_F;
    float p0 = NEG_INF_F;

    if (wave == 0) {
        // ---------------- forward: 63 chunks, rows 0..1007 ----------------
        // shared ml = m+lz (R13's proven ordering): saves 2 adds/column
#define FSTEP(vx, vy, vz, vw, qk) do {                                 \
        const float m1  = fmaxf(A1, O0);                               \
        const float lz1 = LOG2(1.0f + EXP2(-fabsf(A1 - O0)));          \
        const float ml1 = m1 + lz1;                                    \
        const float O1n = (skb1 ? ml1 : A1) + (vy);                    \
        const float psh = shift_up1_ninf(O1n);                         \
        A1 = ml1 + (vw);                                               \
        O1 = O1n;                                                      \
        const float m0  = fmaxf(A0, p0);                               \
        const float lz0 = LOG2(1.0f + EXP2(-fabsf(A0 - p0)));          \
        const float ml0 = m0 + lz0;                                    \
        const float lq0 = l50 ? (qk) : (vz);                           \
        O0 = (skb0 ? ml0 : A0) + (vx);                                 \
        A0 = ml0 + lq0;                                                \
        p0 = psh;                                                      \
    } while (0)
#define RUNF(P) do {                                                       \
        FSTEP(P##v0[0],  P##v0[1],  P##v0[2],  P##v0[3],  P##q0[0]);       \
        FSTEP(P##v1[0],  P##v1[1],  P##v1[2],  P##v1[3],  P##q0[1]);       \
        FSTEP(P##v2[0],  P##v2[1],  P##v2[2],  P##v2[3],  P##q0[2]);       \
        FSTEP(P##v3[0],  P##v3[1],  P##v3[2],  P##v3[3],  P##q0[3]);       \
        FSTEP(P##v4[0],  P##v4[1],  P##v4[2],  P##v4[3],  P##q1[0]);       \
        FSTEP(P##v5[0],  P##v5[1],  P##v5[2],  P##v5[3],  P##q1[1]);       \
        FSTEP(P##v6[0],  P##v6[1],  P##v6[2],  P##v6[3],  P##q1[2]);       \
        FSTEP(P##v7[0],  P##v7[1],  P##v7[2],  P##v7[3],  P##q1[3]);       \
        FSTEP(P##v8[0],  P##v8[1],  P##v8[2],  P##v8[3],  P##q2[0]);       \
        FSTEP(P##v9[0],  P##v9[1],  P##v9[2],  P##v9[3],  P##q2[1]);       \
        FSTEP(P##v10[0], P##v10[1], P##v10[2], P##v10[3], P##q2[2]);       \
        FSTEP(P##v11[0], P##v11[1], P##v11[2], P##v11[3], P##q2[3]);       \
        FSTEP(P##v12[0], P##v12[1], P##v12[2], P##v12[3], P##q3[0]);       \
        FSTEP(P##v13[0], P##v13[1], P##v13[2], P##v13[3], P##q3[1]);       \
        FSTEP(P##v14[0], P##v14[1], P##v14[2], P##v14[3], P##q3[2]);       \
        FSTEP(P##v15[0], P##v15[1], P##v15[2], P##v15[3], P##q3[3]);       \
    } while (0)
        LOADB(X, 0);
        for (int c = 0; c + 1 < 63; c += 2) {
            LOADB(Y, 16 * (c + 1)); VMWAIT(20); RUNF(X);
            LOADB(X, 16 * (c + 2)); VMWAIT(20); RUNF(Y);
        }
        VMWAIT(0); RUNF(X);                  // chunk 62 (rows 992..1007)
#undef RUNF
#undef FSTEP
    } else {
        // ---------------- backward: 62 chunks, rows 1999..1008 ------------
        float bA0 = l50 ? 0.0f : NEG_INF_F;          // bA[100] = 0
        float bA1 = NEG_INF_F;
        float bO0 = NEG_INF_F;
        float bO1 = (lane == 49) ? 0.0f : NEG_INF_F; // bO[99] = 0
#define BSTEP(vx, vy, vz, vw, qk) do {                                 \
        const float x1  = bA1 + (vw);                                  \
        const float y1  = bO1 + (vy);                                  \
        const float m1  = fmaxf(x1, y1);                               \
        const float lz1 = LOG2(1.0f + EXP2(-fabsf(x1 - y1)));          \
        const float L1  = m1 + lz1;                                    \
        const float lq0 = l50 ? (qk) : (vz);                           \
        const float x0  = bA0 + lq0;                                   \
        const float y0  = bO0 + (vx);                                  \
        const float m0  = fmaxf(x0, y0);                               \
        const float lz0 = LOG2(1.0f + EXP2(-fabsf(x0 - y0)));          \
        const float L0  = m0 + lz0;                                    \
        const float t0  = skb0 ? L0 : x0;                              \
        const float psh = shift_dn1_ninf(t0);  /* lane i <- i+1 */     \
        bO0 = skb1 ? L1 : x1;                                          \
        bA0 = l50 ? x0 : L0;                                           \
        bA1 = L1;                                                      \
        bO1 = psh;                                                     \
    } while (0)
#define RUNBK(P) do {                                                      \
        BSTEP(P##v15[0], P##v15[1], P##v15[2], P##v15[3], P##q3[3]);       \
        BSTEP(P##v14[0], P##v14[1], P##v14[2], P##v14[3], P##q3[2]);       \
        BSTEP(P##v13[0], P##v13[1], P##v13[2], P##v13[3], P##q3[1]);       \
        BSTEP(P##v12[0], P##v12[1], P##v12[2], P##v12[3], P##q3[0]);       \
        BSTEP(P##v11[0], P##v11[1], P##v11[2], P##v11[3], P##q2[3]);       \
        BSTEP(P##v10[0], P##v10[1], P##v10[2], P##v10[3], P##q2[2]);       \
        BSTEP(P##v9[0],  P##v9[1],  P##v9[2],  P##v9[3],  P##q2[1]);       \
        BSTEP(P##v8[0],  P##v8[1],  P##v8[2],  P##v8[3],  P##q2[0]);       \
        BSTEP(P##v7[0],  P##v7[1],  P##v7[2],  P##v7[3],  P##q1[3]);       \
        BSTEP(P##v6[0],  P##v6[1],  P##v6[2],  P##v6[3],  P##q1[2]);       \
        BSTEP(P##v5[0],  P##v5[1],  P##v5[2],  P##v5[3],  P##q1[1]);       \
        BSTEP(P##v4[0],  P##v4[1],  P##v4[2],  P##v4[3],  P##q1[0]);       \
        BSTEP(P##v3[0],  P##v3[1],  P##v3[2],  P##v3[3],  P##q0[3]);       \
        BSTEP(P##v2[0],  P##v2[1],  P##v2[2],  P##v2[3],  P##q0[2]);       \
        BSTEP(P##v1[0],  P##v1[1],  P##v1[2],  P##v1[3],  P##q0[1]);       \
        BSTEP(P##v0[0],  P##v0[1],  P##v0[2],  P##v0[3],  P##q0[0]);       \
    } while (0)
        LOADB(X, 1984);
        for (int k = 0; k + 1 < 61; k += 2) {
            LOADB(Y, 1984 - 16 * (k + 1)); VMWAIT(20); RUNBK(X);
            LOADB(X, 1984 - 16 * (k + 2)); VMWAIT(20); RUNBK(Y);
        }
        LOADB(Y, 1008); VMWAIT(20); RUNBK(X);  // chunk 60 (rows 1024..1039)
        VMWAIT(0); RUNBK(Y);                   // chunk 61 (rows 1008..1023)
#undef RUNBK
#undef BSTEP
        sb[0][lane] = bA0; sb[1][lane] = bA1;
        sb[2][lane] = bO0; sb[3][lane] = bO1;
    }
#undef LOADB

    __syncthreads();

    if (wave == 0) {
        // combine: LSE over all states of alpha_1007 + beta_1007
        const float bA0g = sb[0][lane], bA1g = sb[1][lane];
        const float bO0g = sb[2][lane], bO1g = sb[3][lane];
        // lane masks kill garbage (incl. possible NaN) in lanes >= 50
        const float T0 = (lane <= 50) ? A0 + bA0g : NEG_INF_F;
        const float T1 = (lane < 50)  ? A1 + bA1g : NEG_INF_F;
        const float T2 = (lane < 50)  ? O0 + bO0g : NEG_INF_F;
        const float T3 = (lane < 50)  ? O1 + bO1g : NEG_INF_F;
        float M = fmaxf(fmaxf(T0, T1), fmaxf(T2, T3));
        float S = EXP2(T0 - M) + EXP2(T1 - M) + EXP2(T2 - M) + EXP2(T3 - M);
        #pragma unroll
        for (int off = 32; off >= 1; off >>= 1) {
            const float Mo = __shfl_xor(M, off, 64);
            const float So = __shfl_xor(S, off, 64);
            const float Mn = fmaxf(M, Mo);
            S = S * EXP2(M - Mn) + So * EXP2(Mo - Mn);
            M = Mn;
        }
        if (lane == 0) {
            const float LN2 = 0.6931471805599453f;
            atomicAdd(out, -(M + LOG2(S)) * LN2
                               / ((float)T_LEN * (float)BATCH));
        }
    }
}

// ---------------------------------------------------------------- launch
extern "C" void kernel_launch(void* const* d_in, const int* in_sizes, int n_in,
                              void* d_out, int out_size, void* d_ws, size_t ws_size,
                              hipStream_t stream)
{
    const float* inputs  = (const float*)d_in[0];   // (2000,32,128) f32
    const int*   targets = (const int*)d_in[1];     // (32,100) i32
    float*       out     = (float*)d_out;           // scalar f32

    float4* tabA = (float4*)d_ws;                                   // 51.2 MB
    float*  tabB = (float*)((char*)d_ws + (size_t)BATCH * T_LEN * 50 * 16);

    // wt = WLAST + (W0-WLAST)*exp(-NSTEP*ln2/THALF)
    const float wt = (float)(0.1 + 0.9 * exp(-log(2.0) / 10000.0));

    // out zeroed inside stc_emit (idle lane) — no memset dispatch.
    stc_emit<<<dim3(T_LEN / EROWS, BATCH), dim3(64), 0, stream>>>(
        inputs, targets, tabA, tabB, out, wt);
    stc_scan<<<dim3(BATCH), dim3(128), 0, stream>>>(tabA, tabB, targets, out);
}